// Round 1
// baseline (12511.994 us; speedup 1.0000x reference)
//
#include <hip/hip_runtime.h>
#include <hip/hip_bf16.h>
#include <hip/hip_fp16.h>

// LSTM forecast: B=256, T_past=512, HID=512, FEAT=1, future=64 -> 576 steps.
// Grid 256 WGs = 16 batch-groups (bb) x 16 hidden-groups (gb), 1 WG/CU.
// Each WG: 16 batch x 32 hidden. W_hh slice (128 rows x 512 k) persistent in
// registers as fp16 MFMA B-frags. Per-step cross-WG h exchange via global
// double buffer + per-group release/acquire counter.

#define TPAST 512
#define TTOT  576
#define HIDN  512
#define BW    16            // batch per WG
#define HW    32            // hidden per WG
#define NGRP  16            // hidden groups per batch group
#define HSTR  520           // hcur LDS row stride (fp16 elems), pad 8
#define GSTR  132           // gates LDS row stride (fp32), pad 4
#define BATCHN 256

typedef _Float16 half8  __attribute__((ext_vector_type(8)));
typedef _Float16 half2v __attribute__((ext_vector_type(2)));
typedef float    float4v __attribute__((ext_vector_type(4)));
typedef int      int4v  __attribute__((ext_vector_type(4)));

__device__ __forceinline__ float fast_exp(float x) {
    return __builtin_amdgcn_exp2f(x * 1.44269504f);
}
__device__ __forceinline__ float fast_sigmoid(float x) {
    return __builtin_amdgcn_rcpf(1.0f + fast_exp(-x));
}
__device__ __forceinline__ float fast_tanh(float x) {
    return 1.0f - 2.0f * __builtin_amdgcn_rcpf(fast_exp(2.0f * x) + 1.0f);
}

__global__ __launch_bounds__(256, 1)
void lstm_forecast_kernel(const float* __restrict__ xseq,
                          const float* __restrict__ Wih,
                          const float* __restrict__ Whh,
                          const float* __restrict__ bih,
                          const float* __restrict__ bhh,
                          const float* __restrict__ Wdec,
                          const float* __restrict__ bdec,
                          float* __restrict__ out,
                          unsigned int* __restrict__ cnt,
                          _Float16* __restrict__ hbuf)
{
    __shared__ _Float16 hcur[BW * HSTR];   // current h tile, fp16, row=batch
    __shared__ float    gates[BW * GSTR];  // staged MFMA output (16 x 128)
    __shared__ float    xcur[BW];

    const int tid  = threadIdx.x;
    const int bb   = blockIdx.x & 15;      // batch group (same XCD heuristic)
    const int gb   = blockIdx.x >> 4;      // hidden group
    const int lane = tid & 63;
    const int wave = tid >> 6;
    const int m    = lane & 15;            // MFMA A-row / B-col / D-col
    const int q    = lane >> 4;            // MFMA quad

    // ---- persistent W_hh B-fragments: 2 col-blocks x 16 k-steps ----
    half8 Wf[2][16];
    {
        #pragma unroll
        for (int cbi = 0; cbi < 2; ++cbi) {
            const int col = (2 * wave + cbi) * 16 + m;        // 0..127
            const int gt  = col >> 5;                          // 0=i 1=f 2=g 3=o
            const int jl  = col & 31;
            const float* wr = Whh + (gt * HIDN + gb * HW + jl) * HIDN;
            #pragma unroll
            for (int kk = 0; kk < 16; ++kk) {
                const int k0 = kk * 32 + q * 8;
                float4v u = *(const float4v*)(wr + k0);
                float4v v = *(const float4v*)(wr + k0 + 4);
                half8 h;
                h[0] = (_Float16)u[0]; h[1] = (_Float16)u[1];
                h[2] = (_Float16)u[2]; h[3] = (_Float16)u[3];
                h[4] = (_Float16)v[0]; h[5] = (_Float16)v[1];
                h[6] = (_Float16)v[2]; h[7] = (_Float16)v[3];
                Wf[cbi][kk] = h;
            }
        }
    }

    // ---- per-thread elementwise constants: thread -> (batch eb, hidden j0,j0+1)
    const int eb = tid >> 4;
    const int jj = tid & 15;
    const int j0 = 2 * jj;
    float wih_r[2][4], bsum_r[2][4], wd[2];
    #pragma unroll
    for (int p = 0; p < 2; ++p) {
        const int jg = gb * HW + j0 + p;
        #pragma unroll
        for (int gt = 0; gt < 4; ++gt) {
            const int r = gt * HIDN + jg;
            wih_r[p][gt]  = Wih[r];
            bsum_r[p][gt] = bih[r] + bhh[r];
        }
        wd[p] = Wdec[jg];
    }
    const float bdecv = bdec[0];
    float c0 = 0.01f, c1 = 0.01f;

    // ---- init h = 0.01 (fp16) and x for t=0 ----
    {
        const _Float16 hinit = (_Float16)0.01f;
        for (int i = tid; i < BW * HSTR; i += 256) hcur[i] = hinit;
        if (tid < BW) xcur[tid] = xseq[(bb * BW + tid) * TPAST + 0];
    }
    __syncthreads();

    unsigned int* mycnt = cnt + bb * 32;   // 128B-padded counters
    const int bglob_e = bb * BW + eb;

    for (int t = 0; t < TTOT; ++t) {
        // ---- phase 1: MFMA  gates_tile = h (16x512) * W^T (512x128) ----
        float4v acc0 = {0.f, 0.f, 0.f, 0.f};
        float4v acc1 = {0.f, 0.f, 0.f, 0.f};
        const _Float16* arow = hcur + m * HSTR + q * 8;
        #pragma unroll
        for (int kk = 0; kk < 16; ++kk) {
            half8 af = *(const half8*)(arow + kk * 32);
            acc0 = __builtin_amdgcn_mfma_f32_16x16x32_f16(af, Wf[0][kk], acc0, 0, 0, 0);
            acc1 = __builtin_amdgcn_mfma_f32_16x16x32_f16(af, Wf[1][kk], acc1, 0, 0, 0);
        }
        // ---- phase 2: stage gates to LDS (C layout: col=m, row=q*4+r) ----
        {
            const int colbase = wave * 32;
            #pragma unroll
            for (int r = 0; r < 4; ++r) {
                gates[(q * 4 + r) * GSTR + colbase +      m] = acc0[r];
                gates[(q * 4 + r) * GSTR + colbase + 16 + m] = acc1[r];
            }
        }
        __syncthreads();

        // ---- phase 3: elementwise LSTM cell + h store + decoder partial ----
        {
            const float xc = xcur[eb];
            const float* grow = gates + eb * GSTR;

            float gi = grow[      j0] + xc * wih_r[0][0] + bsum_r[0][0];
            float gf = grow[32  + j0] + xc * wih_r[0][1] + bsum_r[0][1];
            float gg = grow[64  + j0] + xc * wih_r[0][2] + bsum_r[0][2];
            float go = grow[96  + j0] + xc * wih_r[0][3] + bsum_r[0][3];
            c0 = fast_sigmoid(gf) * c0 + fast_sigmoid(gi) * fast_tanh(gg);
            const float h0 = fast_sigmoid(go) * fast_tanh(c0);

            gi = grow[      j0 + 1] + xc * wih_r[1][0] + bsum_r[1][0];
            gf = grow[32  + j0 + 1] + xc * wih_r[1][1] + bsum_r[1][1];
            gg = grow[64  + j0 + 1] + xc * wih_r[1][2] + bsum_r[1][2];
            go = grow[96  + j0 + 1] + xc * wih_r[1][3] + bsum_r[1][3];
            c1 = fast_sigmoid(gf) * c1 + fast_sigmoid(gi) * fast_tanh(gg);
            const float h1 = fast_sigmoid(go) * fast_tanh(c1);

            half2v hp; hp[0] = (_Float16)h0; hp[1] = (_Float16)h1;
            *(half2v*)(hbuf + (size_t)(((t + 1) & 1) * BATCHN + bglob_e) * HIDN
                       + gb * HW + j0) = hp;

            float dp = h0 * wd[0] + h1 * wd[1];
            dp += __shfl_down(dp, 8);
            dp += __shfl_down(dp, 4);
            dp += __shfl_down(dp, 2);
            dp += __shfl_down(dp, 1);
            if (jj == 0)
                atomicAdd(out + bglob_e * TTOT + t,
                          dp + (gb == 0 ? bdecv : 0.0f));
        }

        if (t == TTOT - 1) break;

        // ---- phase 4/5: release h writes, group barrier (16 WGs / group) ----
        __threadfence();
        __syncthreads();
        if (tid == 0) {
            __hip_atomic_fetch_add(mycnt, 1u, __ATOMIC_RELEASE,
                                   __HIP_MEMORY_SCOPE_AGENT);
            const unsigned int target = (unsigned int)(NGRP * (t + 1));
            int guard = 0;
            while (__hip_atomic_load(mycnt, __ATOMIC_ACQUIRE,
                                     __HIP_MEMORY_SCOPE_AGENT) < target) {
                __builtin_amdgcn_s_sleep(1);
                if (++guard > (1 << 20)) break;   // hang safety: fail loud, not hung
            }
        }
        __syncthreads();

        // ---- phase 6: reload full h tile (16 x 512 fp16) + next x ----
        {
            const int p1 = (t + 1) & 1;
            const _Float16* hsrc = hbuf + (size_t)(p1 * BATCHN + bb * BW) * HIDN;
            #pragma unroll
            for (int i = 0; i < 4; ++i) {
                const int idx = tid + 256 * i;
                const int row = idx >> 6, ch = idx & 63;
                *(int4v*)(hcur + row * HSTR + ch * 8) =
                    *(const int4v*)(hsrc + row * HIDN + ch * 8);
            }
            if (tid < BW) {
                const int tn = t + 1;
                const int bg = bb * BW + tid;
                xcur[tid] = (tn < TPAST) ? xseq[bg * TPAST + tn]
                                         : out[bg * TTOT + (tn - 1)];
            }
        }
        __syncthreads();
    }
}

extern "C" void kernel_launch(void* const* d_in, const int* in_sizes, int n_in,
                              void* d_out, int out_size, void* d_ws, size_t ws_size,
                              hipStream_t stream) {
    (void)in_sizes; (void)n_in; (void)ws_size;
    const float* xseq = (const float*)d_in[0];
    // d_in[1] = future_n scalar (fixed 64, shapes hardcoded)
    const float* Wih  = (const float*)d_in[2];
    const float* Whh  = (const float*)d_in[3];
    const float* bih  = (const float*)d_in[4];
    const float* bhh  = (const float*)d_in[5];
    const float* Wdec = (const float*)d_in[6];
    const float* bdec = (const float*)d_in[7];
    float* out = (float*)d_out;

    unsigned int* cnt = (unsigned int*)d_ws;                 // 16 groups x 128B
    _Float16* hbuf = (_Float16*)((char*)d_ws + 4096);        // [2][256][512] fp16

    hipMemsetAsync(d_ws, 0, 4096, stream);
    hipMemsetAsync(d_out, 0, (size_t)out_size * sizeof(float), stream);
    lstm_forecast_kernel<<<dim3(256), dim3(256), 0, stream>>>(
        xseq, Wih, Whh, bih, bhh, Wdec, bdec, out, cnt, hbuf);
}

// Round 2
// 2380.343 us; speedup vs baseline: 5.2564x; 5.2564x over previous
//
#include <hip/hip_runtime.h>
#include <hip/hip_fp16.h>

// LSTM forecast: B=256, T_past=512, HID=512, FEAT=1, future=64 -> 576 steps.
// Grid 256 WGs = 16 batch-groups (bb) x 16 hidden-groups (gb), 1 WG/CU.
// Each WG: 16 batch x 32 hidden. W_hh slice (128 rows x 512 k) persistent in
// registers as fp16 MFMA B-frags.
//
// R1 lesson: NO ordered agent-scope atomics / __threadfence anywhere — on
// gfx950 those emit buffer_wbl2/buffer_inv (whole-L2 writeback/invalidate,
// ~20 us/step observed). All cross-WG data moves via RELAXED agent-scope
// atomics (plain global ops with sc0 sc1 -> MALL coherence point, no cache
// maintenance). Release = vmcnt(0) drain (done by __syncthreads) before the
// arrive-add; acquire = program-order issue after spin exit.

#define TPAST 512
#define TTOT  576
#define HIDN  512
#define BW    16            // batch per WG
#define HW    32            // hidden per WG
#define NGRP  16            // hidden groups per batch group
#define HSTR  520           // hcur LDS row stride (fp16 elems); *2B = 1040 = 8*130
#define HSTR64 130          // hcur row stride in u64
#define GSTR  133           // gates LDS row stride (fp32); 133%32=5 -> 2-way max
#define BATCHN 256

typedef _Float16 half8   __attribute__((ext_vector_type(8)));
typedef _Float16 half2v  __attribute__((ext_vector_type(2)));
typedef float    float4v __attribute__((ext_vector_type(4)));

__device__ __forceinline__ float fast_exp(float x) {
    return __builtin_amdgcn_exp2f(x * 1.44269504f);
}
__device__ __forceinline__ float fast_sigmoid(float x) {
    return __builtin_amdgcn_rcpf(1.0f + fast_exp(-x));
}
__device__ __forceinline__ float fast_tanh(float x) {
    return 1.0f - 2.0f * __builtin_amdgcn_rcpf(fast_exp(2.0f * x) + 1.0f);
}

__global__ __launch_bounds__(256, 1)
void lstm_forecast_kernel(const float* __restrict__ xseq,
                          const float* __restrict__ Wih,
                          const float* __restrict__ Whh,
                          const float* __restrict__ bih,
                          const float* __restrict__ bhh,
                          const float* __restrict__ Wdec,
                          const float* __restrict__ bdec,
                          float* __restrict__ out,
                          unsigned int* __restrict__ cnt,
                          unsigned int* __restrict__ hbuf)   // fp16 pairs, [2][256][512]
{
    __shared__ _Float16 hcur[BW * HSTR];   // current h tile, fp16, row=batch
    __shared__ float    gates[BW * GSTR];  // staged MFMA output (16 x 128)
    __shared__ float    wdecs[HIDN];       // W_dec row (512 floats)
    __shared__ float    xcur[BW];

    const int tid  = threadIdx.x;
    const int bb   = blockIdx.x & 15;      // batch group (stays on one XCD — perf only)
    const int gb   = blockIdx.x >> 4;      // hidden group
    const int lane = tid & 63;
    const int wave = tid >> 6;
    const int m    = lane & 15;            // MFMA A-row / D-col
    const int q    = lane >> 4;            // MFMA quad

    // ---- persistent W_hh B-fragments: 2 col-blocks x 16 k-steps (128 VGPRs) ----
    half8 Wf[2][16];
    {
        #pragma unroll
        for (int cbi = 0; cbi < 2; ++cbi) {
            const int col = (2 * wave + cbi) * 16 + m;        // 0..127
            const int gt  = col >> 5;                          // 0=i 1=f 2=g 3=o
            const int jl  = col & 31;
            const float* wr = Whh + (gt * HIDN + gb * HW + jl) * HIDN;
            #pragma unroll
            for (int kk = 0; kk < 16; ++kk) {
                const int k0 = kk * 32 + q * 8;
                float4v u = *(const float4v*)(wr + k0);
                float4v v = *(const float4v*)(wr + k0 + 4);
                half8 h;
                h[0] = (_Float16)u[0]; h[1] = (_Float16)u[1];
                h[2] = (_Float16)u[2]; h[3] = (_Float16)u[3];
                h[4] = (_Float16)v[0]; h[5] = (_Float16)v[1];
                h[6] = (_Float16)v[2]; h[7] = (_Float16)v[3];
                Wf[cbi][kk] = h;
            }
        }
    }

    // ---- per-thread elementwise constants: thread -> (batch eb, hidden j0,j0+1)
    const int eb = tid >> 4;
    const int jj = tid & 15;
    const int j0 = 2 * jj;
    float wih_r[2][4], bsum_r[2][4], wd[2];
    #pragma unroll
    for (int p = 0; p < 2; ++p) {
        const int jg = gb * HW + j0 + p;
        #pragma unroll
        for (int gt = 0; gt < 4; ++gt) {
            const int r = gt * HIDN + jg;
            wih_r[p][gt]  = Wih[r];
            bsum_r[p][gt] = bih[r] + bhh[r];
        }
        wd[p] = Wdec[jg];
    }
    const float bdecv = bdec[0];
    float c0 = 0.01f, c1 = 0.01f;

    // ---- init: h = 0.01 (fp16), W_dec row to LDS, x for t=0 ----
    {
        const _Float16 hinit = (_Float16)0.01f;
        for (int i = tid; i < BW * HSTR; i += 256) hcur[i] = hinit;
        if (tid < HIDN / 256 * 256) { /* nop shape */ }
        for (int i = tid; i < HIDN; i += 256) wdecs[i] = Wdec[i];
        if (tid < BW) xcur[tid] = xseq[(bb * BW + tid) * TPAST + 0];
    }
    __syncthreads();

    unsigned int* mycnt = cnt + bb * 32;   // 128B-spaced counters
    const int bglob_e = bb * BW + eb;

    for (int t = 0; t < TTOT; ++t) {
        // ---- phase 1: MFMA  gates_tile = h (16x512) * W^T (512x128) ----
        float4v acc0 = {0.f, 0.f, 0.f, 0.f};
        float4v acc1 = {0.f, 0.f, 0.f, 0.f};
        const _Float16* arow = hcur + m * HSTR + q * 8;
        #pragma unroll
        for (int kk = 0; kk < 16; ++kk) {
            half8 af = *(const half8*)(arow + kk * 32);
            acc0 = __builtin_amdgcn_mfma_f32_16x16x32_f16(af, Wf[0][kk], acc0, 0, 0, 0);
            acc1 = __builtin_amdgcn_mfma_f32_16x16x32_f16(af, Wf[1][kk], acc1, 0, 0, 0);
        }
        // ---- phase 2: stage gates to LDS (C layout: col=m, row=q*4+r) ----
        {
            const int colbase = wave * 32;
            #pragma unroll
            for (int r = 0; r < 4; ++r) {
                gates[(q * 4 + r) * GSTR + colbase +      m] = acc0[r];
                gates[(q * 4 + r) * GSTR + colbase + 16 + m] = acc1[r];
            }
        }
        __syncthreads();

        // ---- phase 3: LSTM cell + h store (relaxed agent) + decoder partial ----
        {
            const float xc = xcur[eb];
            const float* grow = gates + eb * GSTR;

            float gi = grow[      j0] + xc * wih_r[0][0] + bsum_r[0][0];
            float gf = grow[32  + j0] + xc * wih_r[0][1] + bsum_r[0][1];
            float gg = grow[64  + j0] + xc * wih_r[0][2] + bsum_r[0][2];
            float go = grow[96  + j0] + xc * wih_r[0][3] + bsum_r[0][3];
            c0 = fast_sigmoid(gf) * c0 + fast_sigmoid(gi) * fast_tanh(gg);
            const float h0 = fast_sigmoid(go) * fast_tanh(c0);

            gi = grow[      j0 + 1] + xc * wih_r[1][0] + bsum_r[1][0];
            gf = grow[32  + j0 + 1] + xc * wih_r[1][1] + bsum_r[1][1];
            gg = grow[64  + j0 + 1] + xc * wih_r[1][2] + bsum_r[1][2];
            go = grow[96  + j0 + 1] + xc * wih_r[1][3] + bsum_r[1][3];
            c1 = fast_sigmoid(gf) * c1 + fast_sigmoid(gi) * fast_tanh(gg);
            const float h1 = fast_sigmoid(go) * fast_tanh(c1);

            // h exchange store: one u32 (2 fp16), RELAXED agent -> MALL,
            // no cache maintenance.
            half2v hp; hp[0] = (_Float16)h0; hp[1] = (_Float16)h1;
            const unsigned int bits = __builtin_bit_cast(unsigned int, hp);
            unsigned int* hdst = hbuf
                + (size_t)(((t + 1) & 1) * BATCHN + bglob_e) * (HIDN / 2)
                + (gb * HW + j0) / 2;
            __hip_atomic_store(hdst, bits, __ATOMIC_RELAXED,
                               __HIP_MEMORY_SCOPE_AGENT);

            // decoder partial for out[, t] — fire-and-forget (nothing reads
            // out on-device anymore).
            float dp = h0 * wd[0] + h1 * wd[1];
            dp += __shfl_down(dp, 8);
            dp += __shfl_down(dp, 4);
            dp += __shfl_down(dp, 2);
            dp += __shfl_down(dp, 1);
            if (jj == 0)
                atomicAdd(out + bglob_e * TTOT + t,
                          dp + (gb == 0 ? bdecv : 0.0f));
        }

        if (t == TTOT - 1) break;

        // ---- phase 4: release + arrive + spin (all RELAXED, no wbl2/inv) ----
        __syncthreads();   // compiler drains vmcnt(0) before s_barrier ->
                           // every wave's h stores are at MALL after this
        if (tid == 0) {
            __builtin_amdgcn_s_waitcnt(0);   // belt-and-suspenders drain
            __hip_atomic_fetch_add(mycnt, 1u, __ATOMIC_RELAXED,
                                   __HIP_MEMORY_SCOPE_AGENT);
            const unsigned int target = (unsigned int)(NGRP * (t + 1));
            int guard = 0;
            while (__hip_atomic_load(mycnt, __ATOMIC_RELAXED,
                                     __HIP_MEMORY_SCOPE_AGENT) < target) {
                __builtin_amdgcn_s_sleep(1);
                if (++guard > (1 << 22)) break;   // fail loud, not hung
            }
        }
        __syncthreads();

        // ---- phase 5: reload full h tile (16 x 512 fp16) via relaxed u64 loads ----
        {
            const int p1 = (t + 1) & 1;
            const unsigned long long* hsrc = (const unsigned long long*)hbuf
                + (size_t)(p1 * BATCHN + bb * BW) * (HIDN / 4);
            unsigned long long* hc64 = (unsigned long long*)hcur;
            #pragma unroll
            for (int i = 0; i < 8; ++i) {
                const int w   = tid + 256 * i;     // 0..2047
                const int row = w >> 7;            // 128 u64 per row
                const int col = w & 127;
                hc64[row * HSTR64 + col] =
                    __hip_atomic_load(hsrc + row * (HIDN / 4) + col,
                                      __ATOMIC_RELAXED, __HIP_MEMORY_SCOPE_AGENT);
            }
        }
        __syncthreads();   // hcur ready (drains the LDS writes)

        // ---- phase 6: next x — local decoder dot in future phase (no out read) ----
        {
            const int tn = t + 1;
            if (tn < TPAST) {
                if (tid < BW)
                    xcur[tid] = xseq[(bb * BW + tid) * TPAST + tn];
            } else {
                // x_{tn} = h_tn . W_dec + b_dec, from the fp16 h tile each WG
                // already holds. thread (eb,jj) covers j = jj*32 .. jj*32+31.
                const _Float16* hr = hcur + eb * HSTR + jj * 32;
                const float*    wr = wdecs + jj * 32;
                float dx = 0.f;
                #pragma unroll
                for (int u = 0; u < 4; ++u) {
                    half8 hv = *(const half8*)(hr + u * 8);
                    #pragma unroll
                    for (int e = 0; e < 8; ++e)
                        dx += (float)hv[e] * wr[u * 8 + e];
                }
                dx += __shfl_down(dx, 8);
                dx += __shfl_down(dx, 4);
                dx += __shfl_down(dx, 2);
                dx += __shfl_down(dx, 1);
                if (jj == 0) xcur[eb] = dx + bdecv;
            }
        }
        // no barrier needed here: xcur reads in phase 3 are separated from
        // these writes by the phase-2 __syncthreads; hcur reads in phase 1
        // are separated by the barrier above.
    }
}

extern "C" void kernel_launch(void* const* d_in, const int* in_sizes, int n_in,
                              void* d_out, int out_size, void* d_ws, size_t ws_size,
                              hipStream_t stream) {
    (void)in_sizes; (void)n_in; (void)ws_size;
    const float* xseq = (const float*)d_in[0];
    // d_in[1] = future_n scalar (fixed 64, shapes hardcoded)
    const float* Wih  = (const float*)d_in[2];
    const float* Whh  = (const float*)d_in[3];
    const float* bih  = (const float*)d_in[4];
    const float* bhh  = (const float*)d_in[5];
    const float* Wdec = (const float*)d_in[6];
    const float* bdec = (const float*)d_in[7];
    float* out = (float*)d_out;

    unsigned int* cnt  = (unsigned int*)d_ws;                 // 16 groups x 128B
    unsigned int* hbuf = (unsigned int*)((char*)d_ws + 4096); // [2][256][512] fp16 as u32 pairs

    hipMemsetAsync(d_ws, 0, 4096, stream);
    hipMemsetAsync(d_out, 0, (size_t)out_size * sizeof(float), stream);
    lstm_forecast_kernel<<<dim3(256), dim3(256), 0, stream>>>(
        xseq, Wih, Whh, bih, bhh, Wdec, bdec, out, cnt, hbuf);
}